// Round 5
// baseline (108.077 us; speedup 1.0000x reference)
//
#include <hip/hip_runtime.h>
#include <hip/hip_fp16.h>
#include <math.h>

// ---------------------------------------------------------------------------
// 2-layer GCN on MI355X. N=50000 (<2^16), E=800000, C: 64 -> 64 -> 40.
// hs1[i] = (x@W1)[i]           (fp16, UNSCALED so gemm1 can run before dinv);
// h1b[d] = relu((hs1[d]*dinv[d] + sum_e hs1[src]*dinv[src]) * dinv[d] + b1);
// hs2[i] = (h1b@W2)[i]*dinv[i] (fp16);
// out[d] = log_softmax((hs2[d] + sum_e hs2[src]) * dinv[d] + b2).
//
// 5 dispatches + 1 H2D memcpy node:
//   memcpyAsync: bcur[b] = b*SLACK (replaces the k_init dispatch).
//   k_part_gemm: blocks [0,npart) partition edges into slack dst-buckets.
//                SINGLE-PASS: pass A loads (src,dst) once (4B low-dword reads
//                in the is64 case -- values < 2^16), packs (d16|s16) into an
//                8KB LDS stash + LDS histogram; pass B scatters from the
//                stash. Blocks [npart,..) run the LDS-tiled x@W1 GEMM
//                concurrently (data-independent).
//   k_build:     one wg per 256-row bucket (SHIFT=8 -> 196 blocks): LDS
//                degree count -> 256-wide scan -> row_beg/row_end/dinv ->
//                bucket-local ushort CSR fill.
//   k_gather_relu64: wave/dst-row (1 row/wave, 50000 waves); 8 edges x
//                8 lanes x 16B uint4; 3 shfl_xor butterflies; fused
//                dinv[src] scale + bias + relu -> fp16. Epilogue loads
//                hoisted above the edge loop.
//   k_gemm<40>:  LDS-tiled h1b@W2, dinv-scaled fp16 out.
//   k_gather_lsm40: wave/dst-row; NOW 8 edges x 8 lanes x 16B (q<5 lanes
//                cover the 80B row) -- halves the dependent-load chain vs
//                the old 4 edges x 16 lanes x 8B; fused bias + log_softmax
//                (8-lane reduction) -> fp32.
// Lessons: random small global stores amplify ~10-16x unless bucket-local
// (r3-5); per-lane weight arrays spill to scratch (r6); traffic cuts alone
// were null (r9); block-tile gather+gemm fusion (r10, 47.7us) and wave-GEMV
// fusion (r11, 50.2us) both lose ~10us vs separate 1-row/wave gather; bulk
// RMW pre-scale inside low-parallelism k_build lost ~6us (r12); fixed-cost
// bundle (single-pass part, SHIFT=8, memcpy init, hoists) won 7.2us (r13)
// -> gathers are latency-chain-bound: shorten the dependent-load chain.
// ---------------------------------------------------------------------------

#define SHIFT   8
#define RPB     256
#define NBMAX   256
#define SLACK   8192
#define CHUNK_P 2048

// --- fused: edge partition (blocks < npart) || x@W1 GEMM (rest) -------------
__global__ void k_part_gemm(const int* __restrict__ ei32,
                            int* __restrict__ bcur,
                            unsigned int* __restrict__ ebkt, int E, int nb,
                            int npart,
                            const float* __restrict__ x,
                            const float* __restrict__ W1,
                            __half* __restrict__ hs1, int n) {
    __shared__ __align__(16) float smem[2 * 64 * 68];
    if ((int)blockIdx.x < npart) {
        // ---------------- partition branch (single-pass, LDS stash) --------
        int* cnt   = (int*)smem;          // [256]
        int* rbase = cnt + 256;           // [256]
        int* is64p = rbase + 256;         // [1]
        int* stash = is64p + 1;           // [2048] packed (dst16|src16)
        int t = threadIdx.x;
        cnt[t] = 0;
        if (t == 0) {
            int is64 = 1;
            for (int i = 0; i < 64; ++i)
                if (ei32[2 * i + 1] != 0) { is64 = 0; break; }
            *is64p = is64;
        }
        __syncthreads();
        int is64 = *is64p;
        int lo = blockIdx.x * CHUNK_P;
        int hi = lo + CHUNK_P; if (hi > E) hi = E;
        for (int e = lo + t; e < hi; e += 256) {
            int s, d;
            if (is64) { s = ei32[2 * e]; d = ei32[2 * (E + e)]; }  // low dwords
            else      { s = ei32[e];     d = ei32[E + e]; }
            stash[e - lo] = (int)(((unsigned int)d << 16) | (unsigned int)s);
            atomicAdd(&cnt[d >> SHIFT], 1);
        }
        __syncthreads();
        {
            int c = cnt[t];
            rbase[t] = c ? atomicAdd(&bcur[t], c) : 0;
            cnt[t] = 0;
        }
        __syncthreads();
        for (int e = lo + t; e < hi; e += 256) {
            unsigned int v = (unsigned int)stash[e - lo];
            int b = (int)(v >> 16) >> SHIFT;
            int pos = rbase[b] + atomicAdd(&cnt[b], 1);
            // ebkt entry: (local8 << 16) | src16
            ebkt[pos] = (((v >> 16) & (RPB - 1)) << 16) | (v & 0xffffu);
        }
    } else {
        // ---------------- GEMM branch (x@W1, unscaled fp16 out) -------------
        float* Wl = smem;
        float* Xl = smem + 64 * 68;
        int t  = threadIdx.x;
        int tr = t >> 4, tc = t & 15;
        int base = (blockIdx.x - npart) * 64;

        for (int i = t; i < 64 * 17; i += 256) {
            int k = i / 17, c4 = (i % 17) * 4;
            float4 w = make_float4(0.f, 0.f, 0.f, 0.f);
            if (c4 < 64) w = *(const float4*)&W1[k * 64 + c4];
            *(float4*)&Wl[k * 68 + c4] = w;
        }
        for (int rr = tr; rr < 64; rr += 16) {
            int row = base + rr; if (row >= n) row = n - 1;
            float4 v = *(const float4*)&x[(size_t)row * 64 + tc * 4];
            Xl[(tc * 4 + 0) * 68 + rr] = v.x;
            Xl[(tc * 4 + 1) * 68 + rr] = v.y;
            Xl[(tc * 4 + 2) * 68 + rr] = v.z;
            Xl[(tc * 4 + 3) * 68 + rr] = v.w;
        }
        __syncthreads();

        float acc[4][4] = {{0.f}};
#pragma unroll 8
        for (int k = 0; k < 64; ++k) {
            float4 xv = *(const float4*)&Xl[k * 68 + tr * 4];
            float4 wv = *(const float4*)&Wl[k * 68 + tc * 4];
            acc[0][0] = fmaf(xv.x, wv.x, acc[0][0]);
            acc[0][1] = fmaf(xv.x, wv.y, acc[0][1]);
            acc[0][2] = fmaf(xv.x, wv.z, acc[0][2]);
            acc[0][3] = fmaf(xv.x, wv.w, acc[0][3]);
            acc[1][0] = fmaf(xv.y, wv.x, acc[1][0]);
            acc[1][1] = fmaf(xv.y, wv.y, acc[1][1]);
            acc[1][2] = fmaf(xv.y, wv.z, acc[1][2]);
            acc[1][3] = fmaf(xv.y, wv.w, acc[1][3]);
            acc[2][0] = fmaf(xv.z, wv.x, acc[2][0]);
            acc[2][1] = fmaf(xv.z, wv.y, acc[2][1]);
            acc[2][2] = fmaf(xv.z, wv.z, acc[2][2]);
            acc[2][3] = fmaf(xv.z, wv.w, acc[2][3]);
            acc[3][0] = fmaf(xv.w, wv.x, acc[3][0]);
            acc[3][1] = fmaf(xv.w, wv.y, acc[3][1]);
            acc[3][2] = fmaf(xv.w, wv.z, acc[3][2]);
            acc[3][3] = fmaf(xv.w, wv.w, acc[3][3]);
        }
#pragma unroll
        for (int i = 0; i < 4; ++i) {
            int r = base + tr * 4 + i;
            if (r >= n) break;
            __half2 p0 = __floats2half2_rn(acc[i][0], acc[i][1]);
            __half2 p1 = __floats2half2_rn(acc[i][2], acc[i][3]);
            *(__half2*)&hs1[(size_t)r * 64 + tc * 4]     = p0;
            *(__half2*)&hs1[(size_t)r * 64 + tc * 4 + 2] = p1;
        }
    }
}

// --- per-bucket (256 rows): degree, scan, row_beg/row_end/dinv, CSR fill ----
__global__ void k_build(const unsigned int* __restrict__ ebkt,
                        const int* __restrict__ bcur,
                        int* __restrict__ row_beg, int* __restrict__ row_end,
                        float* __restrict__ dinv,
                        unsigned short* __restrict__ csr_src, int N) {
    __shared__ int cnt[RPB];
    __shared__ int ssum[RPB];
    int t = threadIdx.x, b = blockIdx.x;
    int rows0 = b << SHIFT;
    cnt[t] = 0;
    __syncthreads();
    int lo = b * SLACK, hi = bcur[b];
    for (int e = lo + t; e < hi; e += 256)
        atomicAdd(&cnt[ebkt[e] >> 16], 1);
    __syncthreads();
    int c = cnt[t];
    ssum[t] = c;
    __syncthreads();
    for (int off = 1; off < 256; off <<= 1) {
        int u = (t >= off) ? ssum[t - off] : 0;
        __syncthreads();
        ssum[t] += u;
        __syncthreads();
    }
    int beg = lo + ssum[t] - c;          // exclusive prefix
    int row = rows0 + t;
    if (row < N) {
        row_beg[row] = beg; row_end[row] = beg + c;
        dinv[row] = rsqrtf((float)c + 1.0f);
    }
    cnt[t] = beg;
    __syncthreads();
    for (int e = lo + t; e < hi; e += 256) {
        unsigned int v = ebkt[e];
        int pos = atomicAdd(&cnt[v >> 16], 1);
        csr_src[pos] = (unsigned short)(v & 0xffffu);
    }
}

// --- Gather C=64: 8 edges x 8 lanes x uint4; fused dinv[src]+bias+relu. -----
__global__ void k_gather_relu64(const __half* __restrict__ hs,
                                const int* __restrict__ rbg,
                                const int* __restrict__ ren,
                                const unsigned short* __restrict__ ci,
                                const float* __restrict__ dinv,
                                const float* __restrict__ bias,
                                __half* __restrict__ out, int n) {
    int row = blockIdx.x * 4 + (threadIdx.x >> 6);
    if (row >= n) return;
    int lane = threadIdx.x & 63;
    int g = lane >> 3, q = lane & 7;
    int beg = rbg[row], end = ren[row];

    // hoisted epilogue loads (issue under the gather loop)
    float dv = dinv[row];
    uint4 su = ((const uint4*)(hs + ((size_t)row << 6)))[q];

    float4 aa = make_float4(0.f, 0.f, 0.f, 0.f);
    float4 ab = make_float4(0.f, 0.f, 0.f, 0.f);
    for (int base = beg; base < end; base += 64) {
        int mm = end - base; if (mm > 64) mm = 64;
        int idx = (lane < mm) ? (int)ci[base + lane] : 0;
        for (int j = 0; 8 * j < mm; ++j) {
            int e = 8 * j + g;
            int s = __shfl(idx, e, 64);
            if (base + e < end) {
                float ds = dinv[s];
                uint4 u = ((const uint4*)(hs + ((size_t)s << 6)))[q];
                float2 f0 = __half22float2(*(__half2*)&u.x);
                float2 f1 = __half22float2(*(__half2*)&u.y);
                float2 f2 = __half22float2(*(__half2*)&u.z);
                float2 f3 = __half22float2(*(__half2*)&u.w);
                aa.x = fmaf(f0.x, ds, aa.x); aa.y = fmaf(f0.y, ds, aa.y);
                aa.z = fmaf(f1.x, ds, aa.z); aa.w = fmaf(f1.y, ds, aa.w);
                ab.x = fmaf(f2.x, ds, ab.x); ab.y = fmaf(f2.y, ds, ab.y);
                ab.z = fmaf(f3.x, ds, ab.z); ab.w = fmaf(f3.y, ds, ab.w);
            }
        }
    }
#pragma unroll
    for (int o = 8; o < 64; o <<= 1) {
        aa.x += __shfl_xor(aa.x, o, 64); aa.y += __shfl_xor(aa.y, o, 64);
        aa.z += __shfl_xor(aa.z, o, 64); aa.w += __shfl_xor(aa.w, o, 64);
        ab.x += __shfl_xor(ab.x, o, 64); ab.y += __shfl_xor(ab.y, o, 64);
        ab.z += __shfl_xor(ab.z, o, 64); ab.w += __shfl_xor(ab.w, o, 64);
    }
    // epilogue on all lanes (values identical within each q); lanes<8 store
    float2 s0 = __half22float2(*(__half2*)&su.x);
    float2 s1 = __half22float2(*(__half2*)&su.y);
    float2 s2 = __half22float2(*(__half2*)&su.z);
    float2 s3 = __half22float2(*(__half2*)&su.w);
    float4 bv0 = *(const float4*)&bias[q * 8];
    float4 bv1 = *(const float4*)&bias[q * 8 + 4];
    float v0 = fmaxf((aa.x + s0.x * dv) * dv + bv0.x, 0.f);
    float v1 = fmaxf((aa.y + s0.y * dv) * dv + bv0.y, 0.f);
    float v2 = fmaxf((aa.z + s1.x * dv) * dv + bv0.z, 0.f);
    float v3 = fmaxf((aa.w + s1.y * dv) * dv + bv0.w, 0.f);
    float v4 = fmaxf((ab.x + s2.x * dv) * dv + bv1.x, 0.f);
    float v5 = fmaxf((ab.y + s2.y * dv) * dv + bv1.y, 0.f);
    float v6 = fmaxf((ab.z + s3.x * dv) * dv + bv1.z, 0.f);
    float v7 = fmaxf((ab.w + s3.y * dv) * dv + bv1.w, 0.f);
    if (lane < 8) {
        uint4 st;
        ((__half2*)&st)[0] = __floats2half2_rn(v0, v1);
        ((__half2*)&st)[1] = __floats2half2_rn(v2, v3);
        ((__half2*)&st)[2] = __floats2half2_rn(v4, v5);
        ((__half2*)&st)[3] = __floats2half2_rn(v6, v7);
        ((uint4*)(out + ((size_t)row << 6)))[q] = st;
    }
}

// --- LDS-tiled GEMM (layer 2): hs = (h1b@W2)*dinv, fp16 in/out, COUT=40. ----
template<int COUT>
__global__ void k_gemm(const __half* __restrict__ xin,
                       const float* __restrict__ W,
                       const float* __restrict__ dinv,
                       __half* __restrict__ hs, int n) {
    __shared__ float Wl[64 * 68];
    __shared__ float Xl[64 * 68];
    int t  = threadIdx.x;
    int tr = t >> 4, tc = t & 15;
    int base = blockIdx.x * 64;

    for (int i = t; i < 64 * 17; i += 256) {
        int k = i / 17, c4 = (i % 17) * 4;
        float4 w = make_float4(0.f, 0.f, 0.f, 0.f);
        if (c4 < COUT) w = *(const float4*)&W[k * COUT + c4];
        *(float4*)&Wl[k * 68 + c4] = w;
    }
    for (int rr = tr; rr < 64; rr += 16) {
        int row = base + rr; if (row >= n) row = n - 1;
        uint2 u = *(const uint2*)&xin[(size_t)row * 64 + tc * 4];
        float2 a = __half22float2(*(__half2*)&u.x);
        float2 c = __half22float2(*(__half2*)&u.y);
        Xl[(tc * 4 + 0) * 68 + rr] = a.x;
        Xl[(tc * 4 + 1) * 68 + rr] = a.y;
        Xl[(tc * 4 + 2) * 68 + rr] = c.x;
        Xl[(tc * 4 + 3) * 68 + rr] = c.y;
    }
    __syncthreads();

    float acc[4][4] = {{0.f}};
#pragma unroll 8
    for (int k = 0; k < 64; ++k) {
        float4 xv = *(const float4*)&Xl[k * 68 + tr * 4];
        float4 wv = *(const float4*)&Wl[k * 68 + tc * 4];
        acc[0][0] = fmaf(xv.x, wv.x, acc[0][0]);
        acc[0][1] = fmaf(xv.x, wv.y, acc[0][1]);
        acc[0][2] = fmaf(xv.x, wv.z, acc[0][2]);
        acc[0][3] = fmaf(xv.x, wv.w, acc[0][3]);
        acc[1][0] = fmaf(xv.y, wv.x, acc[1][0]);
        acc[1][1] = fmaf(xv.y, wv.y, acc[1][1]);
        acc[1][2] = fmaf(xv.y, wv.z, acc[1][2]);
        acc[1][3] = fmaf(xv.y, wv.w, acc[1][3]);
        acc[2][0] = fmaf(xv.z, wv.x, acc[2][0]);
        acc[2][1] = fmaf(xv.z, wv.y, acc[2][1]);
        acc[2][2] = fmaf(xv.z, wv.z, acc[2][2]);
        acc[2][3] = fmaf(xv.z, wv.w, acc[2][3]);
        acc[3][0] = fmaf(xv.w, wv.x, acc[3][0]);
        acc[3][1] = fmaf(xv.w, wv.y, acc[3][1]);
        acc[3][2] = fmaf(xv.w, wv.z, acc[3][2]);
        acc[3][3] = fmaf(xv.w, wv.w, acc[3][3]);
    }
#pragma unroll
    for (int i = 0; i < 4; ++i) {
        int r = base + tr * 4 + i;
        if (r >= n) break;
        float dv = dinv[r];
        __half2 p0 = __floats2half2_rn(acc[i][0] * dv, acc[i][1] * dv);
        __half2 p1 = __floats2half2_rn(acc[i][2] * dv, acc[i][3] * dv);
        if (tc * 4 + 3 < COUT) {
            *(__half2*)&hs[(size_t)r * COUT + tc * 4]     = p0;
            *(__half2*)&hs[(size_t)r * COUT + tc * 4 + 2] = p1;
        }
    }
}

// --- Gather C=40 + bias + log_softmax -> fp32. 8 edges x 8 lanes x uint4 ----
// (q<5 lanes cover the 80B row). Dependent-load chain is half the old
// 4-edge x 16-lane shape; softmax reduces over the 8-lane q-group.
__global__ void k_gather_lsm40(const __half* __restrict__ hs,
                               const int* __restrict__ rbg,
                               const int* __restrict__ ren,
                               const unsigned short* __restrict__ ci,
                               const float* __restrict__ dinv,
                               const float* __restrict__ bias,
                               float* __restrict__ out, int n) {
    int row = blockIdx.x * 4 + (threadIdx.x >> 6);
    if (row >= n) return;
    int lane = threadIdx.x & 63;
    int g = lane >> 3, q = lane & 7;
    int beg = rbg[row], end = ren[row];

    // hoisted epilogue loads
    float dv = dinv[row];
    uint4 selfu = make_uint4(0u, 0u, 0u, 0u);
    if (q < 5)
        selfu = ((const uint4*)(hs + (size_t)row * 40))[q];

    float4 aa = make_float4(0.f, 0.f, 0.f, 0.f);
    float4 ab = make_float4(0.f, 0.f, 0.f, 0.f);
    for (int base = beg; base < end; base += 64) {
        int mm = end - base; if (mm > 64) mm = 64;
        int idx = (lane < mm) ? (int)ci[base + lane] : 0;
        for (int j = 0; 8 * j < mm; ++j) {
            int e = 8 * j + g;
            int s = __shfl(idx, e, 64);
            if (q < 5 && base + e < end) {
                uint4 u = ((const uint4*)(hs + (size_t)s * 40))[q];
                float2 f0 = __half22float2(*(__half2*)&u.x);
                float2 f1 = __half22float2(*(__half2*)&u.y);
                float2 f2 = __half22float2(*(__half2*)&u.z);
                float2 f3 = __half22float2(*(__half2*)&u.w);
                aa.x += f0.x; aa.y += f0.y; aa.z += f1.x; aa.w += f1.y;
                ab.x += f2.x; ab.y += f2.y; ab.z += f3.x; ab.w += f3.y;
            }
        }
    }
#pragma unroll
    for (int o = 8; o < 64; o <<= 1) {
        aa.x += __shfl_xor(aa.x, o, 64); aa.y += __shfl_xor(aa.y, o, 64);
        aa.z += __shfl_xor(aa.z, o, 64); aa.w += __shfl_xor(aa.w, o, 64);
        ab.x += __shfl_xor(ab.x, o, 64); ab.y += __shfl_xor(ab.y, o, 64);
        ab.z += __shfl_xor(ab.z, o, 64); ab.w += __shfl_xor(ab.w, o, 64);
    }

    float2 s0 = __half22float2(*(__half2*)&selfu.x);
    float2 s1 = __half22float2(*(__half2*)&selfu.y);
    float2 s2 = __half22float2(*(__half2*)&selfu.z);
    float2 s3 = __half22float2(*(__half2*)&selfu.w);
    float v0 = -INFINITY, v1 = -INFINITY, v2 = -INFINITY, v3 = -INFINITY;
    float v4 = -INFINITY, v5 = -INFINITY, v6 = -INFINITY, v7 = -INFINITY;
    if (q < 5) {
        float4 bv0 = *(const float4*)&bias[q * 8];
        float4 bv1 = *(const float4*)&bias[q * 8 + 4];
        v0 = (aa.x + s0.x) * dv + bv0.x;
        v1 = (aa.y + s0.y) * dv + bv0.y;
        v2 = (aa.z + s1.x) * dv + bv0.z;
        v3 = (aa.w + s1.y) * dv + bv0.w;
        v4 = (ab.x + s2.x) * dv + bv1.x;
        v5 = (ab.y + s2.y) * dv + bv1.y;
        v6 = (ab.z + s3.x) * dv + bv1.z;
        v7 = (ab.w + s3.y) * dv + bv1.w;
    }
    float mx = fmaxf(fmaxf(fmaxf(v0, v1), fmaxf(v2, v3)),
                     fmaxf(fmaxf(v4, v5), fmaxf(v6, v7)));
#pragma unroll
    for (int o = 1; o < 8; o <<= 1) mx = fmaxf(mx, __shfl_xor(mx, o, 64));
    float e0 = 0.f, e1 = 0.f, e2 = 0.f, e3 = 0.f;
    float e4 = 0.f, e5 = 0.f, e6 = 0.f, e7 = 0.f;
    if (q < 5) {
        e0 = expf(v0 - mx); e1 = expf(v1 - mx);
        e2 = expf(v2 - mx); e3 = expf(v3 - mx);
        e4 = expf(v4 - mx); e5 = expf(v5 - mx);
        e6 = expf(v6 - mx); e7 = expf(v7 - mx);
    }
    float sm = ((e0 + e1) + (e2 + e3)) + ((e4 + e5) + (e6 + e7));
#pragma unroll
    for (int o = 1; o < 8; o <<= 1) sm += __shfl_xor(sm, o, 64);
    if (g == 0 && q < 5) {
        float ls = logf(sm);
        float4 r0 = make_float4(v0 - mx - ls, v1 - mx - ls,
                                v2 - mx - ls, v3 - mx - ls);
        float4 r1 = make_float4(v4 - mx - ls, v5 - mx - ls,
                                v6 - mx - ls, v7 - mx - ls);
        *(float4*)&out[(size_t)row * 40 + q * 8]     = r0;
        *(float4*)&out[(size_t)row * 40 + q * 8 + 4] = r1;
    }
}

extern "C" void kernel_launch(void* const* d_in, const int* in_sizes, int n_in,
                              void* d_out, int out_size, void* d_ws, size_t ws_size,
                              hipStream_t stream) {
    const float* x  = (const float*)d_in[0];
    const void*  ei = d_in[1];
    const float* W1 = (const float*)d_in[2];
    const float* b1 = (const float*)d_in[3];
    const float* W2 = (const float*)d_in[4];
    const float* b2 = (const float*)d_in[5];
    float* out = (float*)d_out;

    const int C_IN = 64;
    const int N = in_sizes[0] / C_IN;   // 50000
    const int E = in_sizes[1] / 2;      // 800000
    (void)n_in; (void)out_size; (void)ws_size;

    char* ws = (char*)d_ws;
    size_t off = 0;
    auto alloc = [&](size_t bytes) -> void* {
        void* p = ws + off;
        off += (bytes + 255) & ~(size_t)255;
        return p;
    };
    int*            bcur    = (int*)           alloc(NBMAX * 4);
    unsigned int*   ebkt    = (unsigned int*)  alloc((size_t)NBMAX * SLACK * 4);
    unsigned short* csr_src = (unsigned short*)alloc((size_t)NBMAX * SLACK * 2);
    int*            row_beg = (int*)           alloc((size_t)N * 4);
    int*            row_end = (int*)           alloc((size_t)N * 4);
    float*          dinv    = (float*)         alloc((size_t)N * 4);
    __half*         hs1     = (__half*)        alloc((size_t)N * 64 * 2);
    __half*         h1b     = (__half*)        alloc((size_t)N * 64 * 2);
    __half*         hs2     = (__half*)        alloc((size_t)N * 40 * 2);

    const int nb    = (N + RPB - 1) >> SHIFT;         // 196
    const int ngrid = (N + 63) / 64;                  // 782
    const int npart = (E + CHUNK_P - 1) / CHUNK_P;    // 391

    // bcur init via H2D memcpy node (replaces the k_init dispatch)
    static int h_binit[NBMAX];
    for (int i = 0; i < NBMAX; ++i) h_binit[i] = i * SLACK;
    hipMemcpyAsync(bcur, h_binit, NBMAX * sizeof(int),
                   hipMemcpyHostToDevice, stream);

    k_part_gemm<<<npart + ngrid, 256, 0, stream>>>(
        (const int*)ei, bcur, ebkt, E, nb, npart, x, W1, hs1, N);
    k_build<<<nb, 256, 0, stream>>>(ebkt, bcur, row_beg, row_end, dinv,
                                    csr_src, N);
    k_gather_relu64<<<(N + 3) / 4, 256, 0, stream>>>(
        hs1, row_beg, row_end, csr_src, dinv, b1, h1b, N);
    k_gemm<40><<<ngrid, 256, 0, stream>>>(h1b, W2, dinv, hs2, N);
    k_gather_lsm40<<<(N + 3) / 4, 256, 0, stream>>>(
        hs2, row_beg, row_end, csr_src, dinv, b2, out, N);
}